// Round 1
// 121.543 us; speedup vs baseline: 1.0148x; 1.0148x over previous
//
#include <hip/hip_runtime.h>
#include <math.h>

#define NLAT 46
#define NLON 90
#define CH   256
#define HW   (NLAT*NLON)   // 4140
#define HWP  4160
#define HWT  64            // hw rows per proj block
#define NHT  65            // hw tiles (65*64 = 4160 >= 4140)
#define XSTR 264           // LDS row stride (ushorts)

// attn schedule:
//  heavy lats {0,1,44,45}: one block per (t,wo); 45 per XCD (360 blocks)
//  light lats 2..43: one block per (t, 4-wo group); wave-per-wo (966 units)
#define HEAVY_PER_XCD 45
#define LIGHT_GROUPS_PER_ROW 23          // ceil(90/4)
#define LIGHT_UNITS   (42*LIGHT_GROUPS_PER_ROW)   // 966
#define LIGHT_PER_XCD 121                // ceil(966/8)
#define SLOTS_PER_XCD (HEAVY_PER_XCD + LIGHT_PER_XCD)   // 166

typedef __attribute__((ext_vector_type(8))) short short8;
typedef __attribute__((ext_vector_type(4))) float floatx4;

__device__ __forceinline__ ushort f2bf(float f){
  uint u = __float_as_uint(f);
  u += 0x7fff + ((u >> 16) & 1);      // RNE
  return (ushort)(u >> 16);
}
__device__ __forceinline__ float bf2fs(short s){
  return __uint_as_float(((uint)(ushort)s) << 16);
}

__device__ __forceinline__ int lower_bound_i(const int* __restrict__ a, int n, int key){
  int lo = 0, hi = n;
  while (lo < hi){ int mid = (lo + hi) >> 1; if (a[mid] < key) lo = mid + 1; else hi = mid; }
  return lo;
}

// Fused cast+transpose+GEMM: Out[hw][kout] = sum_c W[kout][c]*X[c][hw] + bias.
// Block = 64 hw x 256 kout; 4 waves each own 64 kout x 64 hw. X transposed
// through LDS (bf16); W fp32 frags loaded from L2 and cast inline (amortized
// over 4 hw-fragments per MFMA group — 2x better than the old 32-hw tile).
__global__ __launch_bounds__(256) void fproj_kernel(
    const float* __restrict__ qo, const float* __restrict__ ki, const float* __restrict__ vi,
    const float* __restrict__ qw, const float* __restrict__ kw, const float* __restrict__ vw,
    const float* __restrict__ qb, const float* __restrict__ kb, const float* __restrict__ vb,
    ushort* __restrict__ qP, ushort* __restrict__ kP, ushort* __restrict__ vP)
{
  const float* X; const float* Wf; const float* Bias; ushort* Out;
  if (blockIdx.y == 0){ X = qo; Wf = qw; Bias = qb; Out = qP; }
  else if (blockIdx.y == 1){ X = ki; Wf = kw; Bias = kb; Out = kP; }
  else { X = vi; Wf = vw; Bias = vb; Out = vP; }

  __shared__ ushort Xs[HWT][XSTR];

  const int tid = threadIdx.x;
  const int hw0 = blockIdx.x * HWT;

  // ---- stage: X[c][hw] fp32 -> Xs[hwL][c] bf16 ----
  {
    int hwL = tid & 63;
    int cb  = tid >> 6;              // 0..3, owns c in [cb*64, cb*64+64)
    int hw  = hw0 + hwL;
    bool ok = hw < HW;
    const float* Xp = X + (size_t)(cb*64)*HW + (ok ? hw : 0);
    #pragma unroll
    for (int gq = 0; gq < 8; gq++){
      short8 pk;
      #pragma unroll
      for (int u = 0; u < 8; u++){
        float f = ok ? Xp[(size_t)(gq*8 + u)*HW] : 0.f;
        pk[u] = (short)f2bf(f);
      }
      *(short8*)(&Xs[hwL][cb*64 + gq*8]) = pk;
    }
  }
  __syncthreads();

  const int lane = tid & 63;
  const int wave = tid >> 6;
  const int lm = lane & 15;
  const int lq = lane >> 4;
  const int kout_w = wave * 64;

  const float* Apf = Wf + (size_t)(kout_w + lm)*CH + lq*8;

  floatx4 acc[4][4];
  #pragma unroll
  for (int i = 0; i < 4; i++)
    #pragma unroll
    for (int j = 0; j < 4; j++) acc[i][j] = (floatx4){0,0,0,0};

  #pragma unroll
  for (int k0 = 0; k0 < 8; k0++){
    short8 a[4], b[4];
    #pragma unroll
    for (int i = 0; i < 4; i++){
      const float* p = Apf + (size_t)i*16*CH + k0*32;
      float4 w0 = *(const float4*)p;
      float4 w1 = *(const float4*)(p + 4);
      a[i][0] = (short)f2bf(w0.x); a[i][1] = (short)f2bf(w0.y);
      a[i][2] = (short)f2bf(w0.z); a[i][3] = (short)f2bf(w0.w);
      a[i][4] = (short)f2bf(w1.x); a[i][5] = (short)f2bf(w1.y);
      a[i][6] = (short)f2bf(w1.z); a[i][7] = (short)f2bf(w1.w);
    }
    #pragma unroll
    for (int j = 0; j < 4; j++)
      b[j] = *(const short8*)(&Xs[j*16 + lm][lq*8 + k0*32]);
    #pragma unroll
    for (int i = 0; i < 4; i++)
      #pragma unroll
      for (int j = 0; j < 4; j++)
        acc[i][j] = __builtin_amdgcn_mfma_f32_16x16x32_bf16(a[i], b[j], acc[i][j], 0, 0, 0);
  }

  // C/D: col(lane&15)=hw, row(lq*4+r)=kout
  #pragma unroll
  for (int i = 0; i < 4; i++){
    int kout = kout_w + i*16 + lq*4;
    float4 bias = *(const float4*)(Bias + kout);
    #pragma unroll
    for (int j = 0; j < 4; j++){
      int hw = hw0 + j*16 + lm;
      if (hw < HW){
        ushort4 o;
        o.x = f2bf(acc[i][j][0] + bias.x);
        o.y = f2bf(acc[i][j][1] + bias.y);
        o.z = f2bf(acc[i][j][2] + bias.z);
        o.w = f2bf(acc[i][j][3] + bias.w);
        *(ushort4*)(Out + (size_t)hw*CH + kout) = o;
      }
    }
  }
}

// ---- attention ----
// Visit metadata (hi*90+wi0, wi0, quad_w[hi]) staged in LDS once per block;
// removes global col_idx load + int-div + quad gather from the hot chain.
__device__ __forceinline__ void load_q16(const ushort* __restrict__ qP, int row, int gl, float* qf){
  const ushort* qrow = qP + (size_t)row * CH + gl*16;
  short8 q0 = *(const short8*)(qrow);
  short8 q1 = *(const short8*)(qrow + 8);
  #pragma unroll
  for (int u = 0; u < 8; u++){ qf[u] = bf2fs(q0[u]); qf[8+u] = bf2fs(q1[u]); }
}

__device__ __forceinline__ void visit(
    const ushort* __restrict__ kP, const ushort* __restrict__ vP,
    const uint* s_p, const float* s_qw,
    int n, int wo, int gl, const float* qf, float& den, float* acc)
{
  uint p  = s_p[n];
  int base = (int)(p & 0xffffu);     // hi*90 + wi0
  int wi0  = (int)(p >> 16);
  int adj  = base + wo - ((wi0 + wo >= NLON) ? NLON : 0);
  size_t off = (size_t)adj * CH + gl*16;
  const short8* kp8 = (const short8*)(kP + off);
  short8 k0 = kp8[0], k1 = kp8[1];
  float s = 0.f;
  #pragma unroll
  for (int u = 0; u < 8; u++){
    s += qf[u]   * bf2fs(k0[u]);
    s += qf[8+u] * bf2fs(k1[u]);
  }
  // reduce across the 16-lane gl-group (partners always share g)
  s += __shfl_xor(s, 1, 64);
  s += __shfl_xor(s, 2, 64);
  s += __shfl_xor(s, 4, 64);
  s += __shfl_xor(s, 8, 64);
  float e = __expf(s) * s_qw[n];
  const short8* vp8 = (const short8*)(vP + off);
  short8 v0 = vp8[0], v1 = vp8[1];
  den += e;
  #pragma unroll
  for (int u = 0; u < 8; u++){
    acc[u]   += e * bf2fs(v0[u]);
    acc[8+u] += e * bf2fs(v1[u]);
  }
}

__global__ __launch_bounds__(256) void attn_kernel(
    const ushort* __restrict__ qP, const ushort* __restrict__ kP, const ushort* __restrict__ vP,
    const float* __restrict__ quad_w, const int* __restrict__ row_ids,
    const int* __restrict__ col_idx, int nnz, float* __restrict__ out)
{
  const int bid  = blockIdx.x;
  const int xcd  = bid & 7;
  const int slot = bid >> 3;

  int t, wo0, heavy;
  if (slot < HEAVY_PER_XCD){
    heavy = 1;
    int hu   = xcd * HEAVY_PER_XCD + slot;
    int hidx = hu / NLON;
    t   = (hidx < 2) ? hidx : 42 + hidx;
    wo0 = hu - hidx * NLON;
  } else {
    heavy = 0;
    int lu = xcd * LIGHT_PER_XCD + (slot - HEAVY_PER_XCD);
    if (lu >= LIGHT_UNITS) return;          // whole block exits together
    int li = lu / LIGHT_GROUPS_PER_ROW;
    t   = li + 2;
    wo0 = (lu - li * LIGHT_GROUPS_PER_ROW) * 4;
  }

  const int tid  = threadIdx.x;
  const int lane = tid & 63;
  const int wave = tid >> 6;
  const int g    = lane >> 4;
  const int gl   = lane & 15;

  const int start = lower_bound_i(row_ids, nnz, t);
  const int end   = lower_bound_i(row_ids, nnz, t + 1);
  const int nv    = end - start;           // max 180

  __shared__ uint  s_p[256];
  __shared__ float s_qw[256];
  __shared__ float sden[4];
  __shared__ float sacc[4][CH];

  for (int n = tid; n < nv; n += 256){
    int ci  = col_idx[start + n];
    int hi  = ci / NLON;
    int wi0 = ci - hi * NLON;
    s_p[n]  = ((uint)wi0 << 16) | (uint)(hi * NLON + wi0);
    s_qw[n] = quad_w[hi];
  }
  __syncthreads();

  if (heavy){
    // one (t,wo) per block: 16 visit-slots (wave*4+g), cross-wave LDS merge
    float qf[16];
    load_q16(qP, t * NLON + wo0, gl, qf);
    float den = 0.f;
    float acc[16];
    #pragma unroll
    for (int u = 0; u < 16; u++) acc[u] = 0.f;

    for (int n = wave*4 + g; n < nv; n += 16)
      visit(kP, vP, s_p, s_qw, n, wo0, gl, qf, den, acc);

    #pragma unroll
    for (int u = 0; u < 16; u++){
      acc[u] += __shfl_xor(acc[u], 16, 64);
      acc[u] += __shfl_xor(acc[u], 32, 64);
    }
    den += __shfl_xor(den, 16, 64);
    den += __shfl_xor(den, 32, 64);

    if (lane == 0) sden[wave] = den;
    if (g == 0){
      #pragma unroll
      for (int u = 0; u < 16; u++) sacc[wave][gl*16 + u] = acc[u];
    }
    __syncthreads();

    const float D   = sden[0] + sden[1] + sden[2] + sden[3];
    const float num = sacc[0][tid] + sacc[1][tid] + sacc[2][tid] + sacc[3][tid];
    out[(size_t)tid * HW + t * NLON + wo0] = num / D;
  } else {
    // wave-per-wo: 4 visit-slots (g), merge stays in-wave, no syncthreads
    const int wo = wo0 + wave;
    if (wo >= NLON) return;                 // tail group (wo0==88): waves 2,3

    float qf[16];
    load_q16(qP, t * NLON + wo, gl, qf);
    float den = 0.f;
    float acc[16];
    #pragma unroll
    for (int u = 0; u < 16; u++) acc[u] = 0.f;

    for (int n = g; n < nv; n += 4)
      visit(kP, vP, s_p, s_qw, n, wo, gl, qf, den, acc);

    #pragma unroll
    for (int u = 0; u < 16; u++){
      acc[u] += __shfl_xor(acc[u], 16, 64);
      acc[u] += __shfl_xor(acc[u], 32, 64);
    }
    den += __shfl_xor(den, 16, 64);
    den += __shfl_xor(den, 32, 64);

    const float invD = 1.0f / den;
    // lane (g,gl) stores channels gl*16 + g*4 + j; explicit cndmask selects
    // (runtime-indexed acc[] would spill to scratch — rule #20)
    #pragma unroll
    for (int j = 0; j < 4; j++){
      float v01 = (g & 1) ? acc[4 + j]  : acc[j];
      float v23 = (g & 1) ? acc[12 + j] : acc[8 + j];
      float val = (g & 2) ? v23 : v01;
      int c = (gl << 4) + (g << 2) + j;
      out[(size_t)c * HW + t * NLON + wo] = val * invD;
    }
  }
}

extern "C" void kernel_launch(void* const* d_in, const int* in_sizes, int n_in,
                              void* d_out, int out_size, void* d_ws, size_t ws_size,
                              hipStream_t stream)
{
  const float* qo   = (const float*)d_in[0];
  const float* ki   = (const float*)d_in[1];
  const float* vi   = (const float*)d_in[2];
  const float* qw   = (const float*)d_in[3];
  const float* kw   = (const float*)d_in[4];
  const float* vw   = (const float*)d_in[5];
  const float* qb   = (const float*)d_in[6];
  const float* kb   = (const float*)d_in[7];
  const float* vb   = (const float*)d_in[8];
  const float* quad = (const float*)d_in[9];
  const int* row_ids = (const int*)d_in[10];
  const int* col_idx = (const int*)d_in[11];
  const int nnz = in_sizes[10];

  ushort* ws = (ushort*)d_ws;
  const size_t TSZ = (size_t)HWP * CH;
  ushort* qP = ws;  ushort* kP = qP + TSZ;  ushort* vP = kP + TSZ;

  fproj_kernel<<<dim3(NHT, 3), 256, 0, stream>>>(qo, ki, vi, qw, kw, vw, qb, kb, vb, qP, kP, vP);
  attn_kernel<<<dim3(8 * SLOTS_PER_XCD), 256, 0, stream>>>(qP, kP, vP, quad, row_ids, col_idx, nnz, (float*)d_out);
}